// Round 6
// baseline (162.881 us; speedup 1.0000x reference)
//
#include <hip/hip_runtime.h>

typedef _Float16 f16x8 __attribute__((ext_vector_type(8)));
typedef _Float16 f16x2 __attribute__((ext_vector_type(2)));
typedef float    f32x4 __attribute__((ext_vector_type(4)));

#define MFMA(a, b, c) __builtin_amdgcn_mfma_f32_16x16x32_f16((a), (b), (c), 0, 0, 0)

__device__ inline f16x8 zero8() {
    f16x8 z;
#pragma unroll
    for (int i = 0; i < 8; ++i) z[i] = (_Float16)0.0f;
    return z;
}

// R2 structure (verified against R3's hardware-proven canonical maps) with the
// R5-proven launch bounds fix. NEVER use (256,2): it spill-corrupts MFMA
// accumulators (R1/R2/R4 all failed with ~0.04-0.05 absmax from this alone).
//  Layer-1 transposed: C1 = W1^T @ inv^T; D-layout row=channel, col=point
//  directly equals layer-2's A-fragment layout -> h1 lives in 16 f16x8 regs.
//  Layer-2 A-slot (ks,quad,j) <-> channel ks*32 + ((j>>2)&1)*16 + quad*4 + (j&3),
//  absorbed into W2f pre-pack (algebra re-verified against R3 canonical maps).
__global__ __launch_bounds__(256, 1)
void DeformationCorrector_78967268704761_kernel(
        const float* __restrict__ F,
        const float* __restrict__ W1, const float* __restrict__ b1,
        const float* __restrict__ W2, const float* __restrict__ b2,
        const float* __restrict__ W3, const float* __restrict__ b3,
        float* __restrict__ out, int N)
{
    __shared__ __align__(16) _Float16 W2f[8][4][64][8];  // 32 KB  b-frags layer2 (absorbed perm)
    __shared__ __align__(16) _Float16 W1f[8][16][8];     // 2 KB   a-frags layer1 (quad0 slice, k=7 -> b1)
    __shared__ __align__(16) _Float16 W3c[4][16][8];     // 1 KB   b-frags layer3 (n<4 compacted)
    __shared__ __align__(16) _Float16 invL[256][8];      // 4 KB   invariants (7 + bias-one)
    __shared__ __align__(16) float    xls[256][4];       // 4 KB   layer3 outputs
    __shared__ __align__(16) _Float16 h2s[4][64][40];    // 20 KB  per-wave h2 transpose slice

    const int tid  = threadIdx.x;
    const int lane = tid & 63;
    const int w    = tid >> 6;
    const int l15  = tid & 15;
    const int quad = (tid >> 4) & 3;

    // ---------------- weight pre-pack (once per block) ----------------
    for (int m = tid; m < 128 * 128; m += 256) {        // W2[c][n] -> frag layout (absorbed perm)
        int c = m >> 7, n = m & 127;
        int ks = c >> 5, rem = c & 31;
        int j = ((rem >> 4) & 1) * 4 + (rem & 3);
        int q = (rem >> 2) & 3;
        W2f[n >> 4][ks][q * 16 + (n & 15)][j] = (_Float16)W2[m];
    }
    for (int f = tid; f < 1024; f += 256) {             // W1^T a-frags + b1 at k=7
        int mt = f >> 7, l = (f >> 3) & 15, j = f & 7;
        int ch = mt * 16 + l;
        W1f[mt][l][j] = (_Float16)((j < 7) ? W1[j * 128 + ch] : b1[ch]);
    }
    for (int f = tid; f < 512; f += 256) {              // W3 b-frags (h2s col space c''=2*l+(nt2&1))
        int c2 = f >> 2, n3 = f & 3;
        int nt2 = c2 >> 4, l = c2 & 15;
        int s = nt2 >> 1, ch = l * 2 + (nt2 & 1);
        W3c[s][(ch >> 3) * 4 + n3][ch & 7] = (_Float16)W3[c2 * 4 + n3];
    }
    float b2r[8];
#pragma unroll
    for (int nt = 0; nt < 8; ++nt) b2r[nt] = b2[nt * 16 + l15];
    const float b3v = (l15 < 4) ? b3[l15] : 0.f;
    __syncthreads();   // only barrier; main loop LDS traffic is wave-private

    const int ntiles = (N + 255) >> 8;
    for (int tile = blockIdx.x; tile < ntiles; tile += (int)gridDim.x) {
        const int p = tile * 256 + tid;

        // ---------------- phase A: polar + invariants (fp32) ----------------
        float a, b, c, d;
        if (p < N) {
            const float4 f4 = *(const float4*)(F + 4ll * p);
            a = f4.x; b = f4.y; c = f4.z; d = f4.w;
        } else { a = 1.f; b = 0.f; c = 0.f; d = 1.f; }
        const float x1 = a + d, y1 = c - b, x2 = a - d, y2 = c + b;
        const float h1v = sqrtf(x1 * x1 + y1 * y1);
        const float h2v = sqrtf(x2 * x2 + y2 * y2);
        const float s1 = 0.5f * (h1v + h2v), s2 = 0.5f * (h1v - h2v);
        const float ir = 1.0f / h1v;              // h1v ~ 2 (det F > 0)
        const float Rc = x1 * ir, Rs = y1 * ir;   // R = [[Rc,-Rs],[Rs,Rc]]
        f16x8 iv;
        iv[0] = (_Float16)(s1 - 1.f);
        iv[1] = (_Float16)(s2 - 1.f);
        iv[2] = (_Float16)(a * a + c * c - 1.f);
        const float i3 = a * b + c * d;
        iv[3] = (_Float16)i3;
        iv[4] = (_Float16)i3;
        iv[5] = (_Float16)(b * b + d * d - 1.f);
        iv[6] = (_Float16)(a * d - b * c - 1.f);
        iv[7] = (_Float16)1.0f;                    // bias channel
        *(f16x8*)(&invL[tid][0]) = iv;

        // ---------------- layer 1 (transposed): h1 kept in regs ----------------
        f16x8 binv[4];
#pragma unroll
        for (int nt = 0; nt < 4; ++nt)
            binv[nt] = (quad == 0) ? *(const f16x8*)(&invL[w * 64 + nt * 16 + l15][0])
                                   : zero8();
        f16x8 h1f[4][4];   // [point-tile][ks] = layer-2 A-fragments
#pragma unroll
        for (int mt = 0; mt < 8; ++mt) {
            const f16x8 af = (quad == 0) ? *(const f16x8*)(&W1f[mt][l15][0]) : zero8();
#pragma unroll
            for (int nt = 0; nt < 4; ++nt) {
                f32x4 cz = {0.f, 0.f, 0.f, 0.f};
                const f32x4 cc = MFMA(af, binv[nt], cz);
#pragma unroll
                for (int r = 0; r < 4; ++r)
                    h1f[nt][mt >> 1][(mt & 1) * 4 + r] = (_Float16)fmaxf(cc[r], 0.f);
            }
        }

        // ---------------- layers 2+3 interleaved ----------------
        f32x4 acc3[4];
#pragma unroll
        for (int mt = 0; mt < 4; ++mt) acc3[mt] = (f32x4){0.f, 0.f, 0.f, 0.f};

#pragma unroll
        for (int s = 0; s < 4; ++s) {
            f32x4 a2[2][4];
#pragma unroll
            for (int h = 0; h < 2; ++h)
#pragma unroll
                for (int mt = 0; mt < 4; ++mt) a2[h][mt] = (f32x4){0.f, 0.f, 0.f, 0.f};
#pragma unroll
            for (int h = 0; h < 2; ++h) {
                const int nt2 = 2 * s + h;
#pragma unroll
                for (int ks = 0; ks < 4; ++ks) {
                    const f16x8 bf = *(const f16x8*)(&W2f[nt2][ks][lane][0]);
#pragma unroll
                    for (int mt = 0; mt < 4; ++mt)
                        a2[h][mt] = MFMA(h1f[mt][ks], bf, a2[h][mt]);
                }
            }
            // bias + relu + transpose 2 channel-tiles into per-wave slice
            const float bb0 = b2r[2 * s], bb1 = b2r[2 * s + 1];
#pragma unroll
            for (int mt = 0; mt < 4; ++mt) {
#pragma unroll
                for (int r = 0; r < 4; ++r) {
                    f16x2 pw;
                    pw[0] = (_Float16)fmaxf(a2[0][mt][r] + bb0, 0.f);
                    pw[1] = (_Float16)fmaxf(a2[1][mt][r] + bb1, 0.f);
                    *(f16x2*)(&h2s[w][mt * 16 + quad * 4 + r][l15 * 2]) = pw;
                }
            }
            // layer-3 partial K (32 channels of this slice)
            const f16x8 bw3 = (l15 < 4) ? *(const f16x8*)(&W3c[s][quad * 4 + l15][0])
                                        : zero8();
#pragma unroll
            for (int mt = 0; mt < 4; ++mt) {
                const f16x8 ah = *(const f16x8*)(&h2s[w][mt * 16 + l15][quad * 8]);
                acc3[mt] = MFMA(ah, bw3, acc3[mt]);
            }
        }

        // ---------------- epilogue: x -> symmetrize -> R@x + F ----------------
#pragma unroll
        for (int mt = 0; mt < 4; ++mt)
#pragma unroll
            for (int r = 0; r < 4; ++r)
                if (l15 < 4)
                    xls[w * 64 + mt * 16 + quad * 4 + r][l15] = acc3[mt][r] + b3v;

        const float4 xv = *(const float4*)(&xls[w * 64 + lane][0]);
        const float xm  = 0.5f * (xv.y + xv.z);
        const float d00 = Rc * xv.x - Rs * xm;
        const float d01 = Rc * xm   - Rs * xv.w;
        const float d10 = Rs * xv.x + Rc * xm;
        const float d11 = Rs * xm   + Rc * xv.w;
        if (p < N) {
            float4 o;
            o.x = a + d00; o.y = b + d01; o.z = c + d10; o.w = d + d11;
            *(float4*)(out + 4ll * p) = o;
        }
    }
}

extern "C" void kernel_launch(void* const* d_in, const int* in_sizes, int n_in,
                              void* d_out, int out_size, void* d_ws, size_t ws_size,
                              hipStream_t stream) {
    const float* F  = (const float*)d_in[0];
    const float* W1 = (const float*)d_in[1];
    const float* b1 = (const float*)d_in[2];
    const float* W2 = (const float*)d_in[3];
    const float* b2 = (const float*)d_in[4];
    const float* W3 = (const float*)d_in[5];
    const float* b3 = (const float*)d_in[6];
    float* out = (float*)d_out;
    const int N = in_sizes[0] / 4;
    const int ntiles = (N + 255) / 256;
    const int grid = ntiles < 1024 ? ntiles : 1024;
    DeformationCorrector_78967268704761_kernel<<<grid, 256, 0, stream>>>(
        F, W1, b1, W2, b2, W3, b3, out, N);
}

// Round 7
// 161.374 us; speedup vs baseline: 1.0093x; 1.0093x over previous
//
#include <hip/hip_runtime.h>

typedef _Float16 f16x8 __attribute__((ext_vector_type(8)));
typedef _Float16 f16x2 __attribute__((ext_vector_type(2)));
typedef float    f32x4 __attribute__((ext_vector_type(4)));

#define MFMA(a, b, c) __builtin_amdgcn_mfma_f32_16x16x32_f16((a), (b), (c), 0, 0, 0)

__device__ inline f16x8 zero8() {
    f16x8 z;
#pragma unroll
    for (int i = 0; i < 8; ++i) z[i] = (_Float16)0.0f;
    return z;
}

// R6 structure with LDS cut 63 KB -> 55 KB: invL (4 KB) and xls (4 KB) are
// aliased into the per-wave scratch slice (time-disjoint, wave-private; DS ops
// within a wave are in-order so the WAR through the alias is safe). R6's 63 KB
// meant 2 blocks needed 129 KB > the ~128 KB usable pool -> 1 block/CU (occ
// 10.6%). NEVER use __launch_bounds__(256,2): spill-corrupts accumulators.
__global__ __launch_bounds__(256, 1)
void DeformationCorrector_78967268704761_kernel(
        const float* __restrict__ F,
        const float* __restrict__ W1, const float* __restrict__ b1,
        const float* __restrict__ W2, const float* __restrict__ b2,
        const float* __restrict__ W3, const float* __restrict__ b3,
        float* __restrict__ out, int N)
{
    __shared__ __align__(16) _Float16 W2f[8][4][64][8];  // 32 KB  b-frags layer2 (absorbed perm)
    __shared__ __align__(16) _Float16 W1f[8][16][8];     // 2 KB   a-frags layer1 (quad0 slice, k=7 -> b1)
    __shared__ __align__(16) _Float16 W3c[4][16][8];     // 1 KB   b-frags layer3 (n<4 compacted)
    __shared__ __align__(16) _Float16 scr[4][2560];      // 20 KB  per-wave scratch: invL / h2s / xls views

    const int tid  = threadIdx.x;
    const int lane = tid & 63;
    const int w    = tid >> 6;
    const int l15  = tid & 15;
    const int quad = (tid >> 4) & 3;

    _Float16* const invp = &scr[w][0];        // view 1: 64 rows x 8 f16 (1 KB)
    _Float16* const h2p  = &scr[w][0];        // view 2: 64 rows x 40 f16 (5 KB)
    float*    const xf   = (float*)&scr[w][0];// view 3: 64 rows x 4 f32 (1 KB)

    // ---------------- weight pre-pack (once per block) ----------------
    for (int m = tid; m < 128 * 128; m += 256) {        // W2[c][n] -> frag layout (absorbed perm)
        int c = m >> 7, n = m & 127;
        int ks = c >> 5, rem = c & 31;
        int j = ((rem >> 4) & 1) * 4 + (rem & 3);
        int q = (rem >> 2) & 3;
        W2f[n >> 4][ks][q * 16 + (n & 15)][j] = (_Float16)W2[m];
    }
    for (int f = tid; f < 1024; f += 256) {             // W1^T a-frags + b1 at k=7
        int mt = f >> 7, l = (f >> 3) & 15, j = f & 7;
        int ch = mt * 16 + l;
        W1f[mt][l][j] = (_Float16)((j < 7) ? W1[j * 128 + ch] : b1[ch]);
    }
    for (int f = tid; f < 512; f += 256) {              // W3 b-frags (h2s col space c''=2*l+(nt2&1))
        int c2 = f >> 2, n3 = f & 3;
        int nt2 = c2 >> 4, l = c2 & 15;
        int s = nt2 >> 1, ch = l * 2 + (nt2 & 1);
        W3c[s][(ch >> 3) * 4 + n3][ch & 7] = (_Float16)W3[c2 * 4 + n3];
    }
    float b2r[8];
#pragma unroll
    for (int nt = 0; nt < 8; ++nt) b2r[nt] = b2[nt * 16 + l15];
    const float b3v = (l15 < 4) ? b3[l15] : 0.f;
    __syncthreads();   // only barrier; main loop LDS traffic is wave-private

    const int ntiles = (N + 255) >> 8;
    for (int tile = blockIdx.x; tile < ntiles; tile += (int)gridDim.x) {
        const int p = tile * 256 + tid;

        // ---------------- phase A: polar + invariants (fp32) ----------------
        float a, b, c, d;
        if (p < N) {
            const float4 f4 = *(const float4*)(F + 4ll * p);
            a = f4.x; b = f4.y; c = f4.z; d = f4.w;
        } else { a = 1.f; b = 0.f; c = 0.f; d = 1.f; }
        const float x1 = a + d, y1 = c - b, x2 = a - d, y2 = c + b;
        const float h1v = sqrtf(x1 * x1 + y1 * y1);
        const float h2v = sqrtf(x2 * x2 + y2 * y2);
        const float s1 = 0.5f * (h1v + h2v), s2 = 0.5f * (h1v - h2v);
        const float ir = 1.0f / h1v;              // h1v ~ 2 (det F > 0)
        const float Rc = x1 * ir, Rs = y1 * ir;   // R = [[Rc,-Rs],[Rs,Rc]]
        f16x8 iv;
        iv[0] = (_Float16)(s1 - 1.f);
        iv[1] = (_Float16)(s2 - 1.f);
        iv[2] = (_Float16)(a * a + c * c - 1.f);
        const float i3 = a * b + c * d;
        iv[3] = (_Float16)i3;
        iv[4] = (_Float16)i3;
        iv[5] = (_Float16)(b * b + d * d - 1.f);
        iv[6] = (_Float16)(a * d - b * c - 1.f);
        iv[7] = (_Float16)1.0f;                    // bias channel
        *(f16x8*)(&invp[lane * 8]) = iv;

        // ---------------- layer 1 (transposed): h1 kept in regs ----------------
        f16x8 binv[4];
#pragma unroll
        for (int nt = 0; nt < 4; ++nt)
            binv[nt] = (quad == 0) ? *(const f16x8*)(&invp[(nt * 16 + l15) * 8])
                                   : zero8();
        f16x8 h1f[4][4];   // [point-tile][ks] = layer-2 A-fragments
#pragma unroll
        for (int mt = 0; mt < 8; ++mt) {
            const f16x8 af = (quad == 0) ? *(const f16x8*)(&W1f[mt][l15][0]) : zero8();
#pragma unroll
            for (int nt = 0; nt < 4; ++nt) {
                f32x4 cz = {0.f, 0.f, 0.f, 0.f};
                const f32x4 cc = MFMA(af, binv[nt], cz);
#pragma unroll
                for (int r = 0; r < 4; ++r)
                    h1f[nt][mt >> 1][(mt & 1) * 4 + r] = (_Float16)fmaxf(cc[r], 0.f);
            }
        }

        // ---------------- layers 2+3 interleaved ----------------
        f32x4 acc3[4];
#pragma unroll
        for (int mt = 0; mt < 4; ++mt) acc3[mt] = (f32x4){0.f, 0.f, 0.f, 0.f};

#pragma unroll
        for (int s = 0; s < 4; ++s) {
            f32x4 a2[2][4];
#pragma unroll
            for (int h = 0; h < 2; ++h)
#pragma unroll
                for (int mt = 0; mt < 4; ++mt) a2[h][mt] = (f32x4){0.f, 0.f, 0.f, 0.f};
#pragma unroll
            for (int h = 0; h < 2; ++h) {
                const int nt2 = 2 * s + h;
#pragma unroll
                for (int ks = 0; ks < 4; ++ks) {
                    const f16x8 bf = *(const f16x8*)(&W2f[nt2][ks][lane][0]);
#pragma unroll
                    for (int mt = 0; mt < 4; ++mt)
                        a2[h][mt] = MFMA(h1f[mt][ks], bf, a2[h][mt]);
                }
            }
            // bias + relu + transpose 2 channel-tiles into per-wave slice
            const float bb0 = b2r[2 * s], bb1 = b2r[2 * s + 1];
#pragma unroll
            for (int mt = 0; mt < 4; ++mt) {
#pragma unroll
                for (int r = 0; r < 4; ++r) {
                    f16x2 pw;
                    pw[0] = (_Float16)fmaxf(a2[0][mt][r] + bb0, 0.f);
                    pw[1] = (_Float16)fmaxf(a2[1][mt][r] + bb1, 0.f);
                    *(f16x2*)(&h2p[(mt * 16 + quad * 4 + r) * 40 + l15 * 2]) = pw;
                }
            }
            // layer-3 partial K (32 channels of this slice)
            const f16x8 bw3 = (l15 < 4) ? *(const f16x8*)(&W3c[s][quad * 4 + l15][0])
                                        : zero8();
#pragma unroll
            for (int mt = 0; mt < 4; ++mt) {
                const f16x8 ah = *(const f16x8*)(&h2p[(mt * 16 + l15) * 40 + quad * 8]);
                acc3[mt] = MFMA(ah, bw3, acc3[mt]);
            }
        }

        // ---------------- epilogue: x -> symmetrize -> R@x + F ----------------
#pragma unroll
        for (int mt = 0; mt < 4; ++mt)
#pragma unroll
            for (int r = 0; r < 4; ++r)
                if (l15 < 4)
                    xf[(mt * 16 + quad * 4 + r) * 4 + l15] = acc3[mt][r] + b3v;

        const float4 xv = *(const float4*)(&xf[lane * 4]);
        const float xm  = 0.5f * (xv.y + xv.z);
        const float d00 = Rc * xv.x - Rs * xm;
        const float d01 = Rc * xm   - Rs * xv.w;
        const float d10 = Rs * xv.x + Rc * xm;
        const float d11 = Rs * xm   + Rc * xv.w;
        if (p < N) {
            float4 o;
            o.x = a + d00; o.y = b + d01; o.z = c + d10; o.w = d + d11;
            *(float4*)(out + 4ll * p) = o;
        }
    }
}

extern "C" void kernel_launch(void* const* d_in, const int* in_sizes, int n_in,
                              void* d_out, int out_size, void* d_ws, size_t ws_size,
                              hipStream_t stream) {
    const float* F  = (const float*)d_in[0];
    const float* W1 = (const float*)d_in[1];
    const float* b1 = (const float*)d_in[2];
    const float* W2 = (const float*)d_in[3];
    const float* b2 = (const float*)d_in[4];
    const float* W3 = (const float*)d_in[5];
    const float* b3 = (const float*)d_in[6];
    float* out = (float*)d_out;
    const int N = in_sizes[0] / 4;
    const int ntiles = (N + 255) / 256;
    const int grid = ntiles < 1024 ? ntiles : 1024;
    DeformationCorrector_78967268704761_kernel<<<grid, 256, 0, stream>>>(
        F, W1, b1, W2, b2, W3, b3, out, N);
}